// Round 5
// baseline (156.800 us; speedup 1.0000x reference)
//
#include <hip/hip_runtime.h>
#include <hip/hip_bf16.h>
#include <math.h>

// Problem constants: B=32 V=512 K=16 D=128 E=32 NE=8192 -> BV=16384 vertices
#define NLSTR 136   // LDS row stride (ushorts) for 16x128 tiles

typedef __bf16 bf16x8 __attribute__((ext_vector_type(8)));
typedef float f32x4 __attribute__((ext_vector_type(4)));
typedef float f32x16 __attribute__((ext_vector_type(16)));
typedef unsigned short ushort8v __attribute__((ext_vector_type(8)));

union FragU { ushort8v u; bf16x8 b; };

static __device__ inline unsigned short f2bf(float f){
  unsigned u = __float_as_uint(f);
  u += 0x7fffu + ((u >> 16) & 1u);   // RNE
  return (unsigned short)(u >> 16);
}
static __device__ inline float bf2f(unsigned short u){
  return __uint_as_float(((unsigned)u) << 16);
}
// packed f32x2 -> bf16x2 (v_cvt_pk_bf16_f32)
static __device__ inline unsigned pk2(float a, float b){
  union { __hip_bfloat162 h; unsigned u; } r;
  r.h = __float22bfloat162_rn(float2{a, b});
  return r.u;
}
static __device__ inline ushort8v pkcvt8(float4 a, float4 b){
  union { unsigned u[4]; ushort8v v; } r;
  r.u[0] = pk2(a.x, a.y); r.u[1] = pk2(a.z, a.w);
  r.u[2] = pk2(b.x, b.y); r.u[3] = pk2(b.z, b.w);
  return r.v;
}

// tanh-form GELU (max err ~3e-4 vs exact erf-GELU)
static __device__ inline float gelu_f(float x){
  float u = x * x;
  float p = fmaf(u, 0.07135481283f, 1.5957691216f);
  float t = x * p;
  float e = __builtin_amdgcn_exp2f(t * -1.44269504f);
  return x * __builtin_amdgcn_rcpf(1.0f + e);
}

// ---------------- prep: bf16 vertex table + fragment-order bf16 weights ----------------
// w1f: 32x32x16 B-frags. frag (kc*4+nc2), elem j of lane: W1[(nc2*32+(lane&31))*160 + kc*16 + (lane>>5)*8 + j]
// w2f/w3f: 16x16x32 B-frags. frag (kc*8+nc), elem j of lane: W[(nc*16+(lane&15))*rowlen + kc*32 + (lane>>4)*8 + j]
__global__ __launch_bounds__(256) void prep_kernel(
    const float* __restrict__ vf, const float* __restrict__ W1,
    const float* __restrict__ W2, const float* __restrict__ W3,
    unsigned short* __restrict__ vfbf, unsigned short* __restrict__ w1f,
    unsigned short* __restrict__ w2f, unsigned short* __restrict__ w3f)
{
  int t = blockIdx.x * 256 + threadIdx.x;
  if (t < 262144){                       // 16384*128 / 8
    const float4* src = (const float4*)vf;
    float4 x = src[t * 2], y = src[t * 2 + 1];
    *(ushort8v*)(vfbf + t * 8) = pkcvt8(x, y);
    return;
  }
  int t2 = t - 262144;
  const float* s;
  unsigned short* d;
  if (t2 < 2560){                        // w1f: 10kc x 4nc2, 32x32x16 layout
    int fragid = t2 >> 6, lane = t2 & 63;
    int kc = fragid >> 2, nc2 = fragid & 3, n = lane & 31, h = lane >> 5;
    s = W1 + (nc2 * 32 + n) * 160 + kc * 16 + h * 8;
    d = w1f + t2 * 8;
  } else if (t2 < 6656){                 // w2f: 8kc x 8nc, 16x16x32 layout
    int t3 = t2 - 2560;
    int fragid = t3 >> 6, lane = t3 & 63;
    int kc = fragid >> 3, nc = fragid & 7, col = lane & 15, quad = lane >> 4;
    s = W2 + (nc * 16 + col) * 256 + kc * 32 + quad * 8;
    d = w2f + t3 * 8;
  } else if (t2 < 8704){                 // w3f: 4kc x 8nc, 16x16x32 layout
    int t3 = t2 - 6656;
    int fragid = t3 >> 6, lane = t3 & 63;
    int kc = fragid >> 3, nc = fragid & 7, col = lane & 15, quad = lane >> 4;
    s = W3 + (nc * 16 + col) * 128 + kc * 32 + quad * 8;
    d = w3f + t3 * 8;
  } else return;
#pragma unroll
  for (int j = 0; j < 8; j++) d[j] = f2bf(s[j]);
}

// ---------------- fused ----------------
// grid 1024 x 256thr. Block = 16 vertices. Stage1: wave wid owns vertices wid*4..+3,
// TWO vertices per MFMA (32x32x16, M=32: rows 0-15 vertex A, 16-31 vertex B).
// w1f staged in LDS per block (kills 328MB L1 B-frag stream).
// Pair-1 gathers issued before pair-0 epilogue (hides ~900cy behind GELU VALU).
__global__ __launch_bounds__(256) void fused_kernel(
    const unsigned short* __restrict__ vfbf,
    const int* __restrict__ aadj, const int* __restrict__ badj,
    const float* __restrict__ edge, const float* __restrict__ nbs,
    const float* __restrict__ h0,
    const unsigned short* __restrict__ w1f, const unsigned short* __restrict__ w2f,
    const unsigned short* __restrict__ w3f,
    const float* __restrict__ b1, const float* __restrict__ b2, const float* __restrict__ b3,
    const float* __restrict__ lamda, const float* __restrict__ alpha,
    const int* __restrict__ lval,
    float* __restrict__ out)
{
  __shared__ __align__(16) ushort8v w1s[2560];                 // 40 KB
  __shared__ __align__(16) unsigned short nl_lds[16 * NLSTR];  // 4.25 KB
  __shared__ __align__(16) unsigned short sup_lds[16 * NLSTR]; // 4.25 KB
  const int wid  = threadIdx.x >> 6;
  const int lane = threadIdx.x & 63;
  const int n32  = lane & 31;
  const int h    = lane >> 5;
  const int nb   = lane & 15;
  const int vsel = (lane >> 4) & 1;
  const int col  = lane & 15;
  const int quad = lane >> 4;
  const int v0   = blockIdx.x * 16;

  // ---- stage w1f into LDS (coalesced; 256 thr x 10 x 16B) ----
  {
    const ushort8v* src = (const ushort8v*)w1f;
#pragma unroll
    for (int i = 0; i < 10; i++)
      w1s[threadIdx.x + 256 * i] = src[threadIdx.x + 256 * i];
  }

  float b1v[4];
#pragma unroll
  for (int nc2 = 0; nc2 < 4; nc2++) b1v[nc2] = b1[nc2 * 32 + n32];

  const float4* nbs4 = (const float4*)nbs;
  const int vA0 = v0 + wid * 4;          // pair 0 = (vA0, vA0+1), pair 1 = (vA0+2, vA0+3)

  // ---- pair-0 gathers issued before the w1s barrier (independent of LDS) ----
  const int a0 = aadj[(vA0 + vsel) * 16 + nb];
  const int e0 = badj[(vA0 + vsel) * 16 + nb];
  ushort8v av0[8];
  {
    const ushort8v* arow = (const ushort8v*)(vfbf + (size_t)a0 * 128 + h * 8);
#pragma unroll
    for (int kc = 0; kc < 8; kc++) av0[kc] = arow[kc * 2];
  }
  float4 e0a = *(const float4*)(edge + (size_t)e0 * 32 + h * 8);
  float4 e0b = *(const float4*)(edge + (size_t)e0 * 32 + h * 8 + 4);
  float4 e0c = *(const float4*)(edge + (size_t)e0 * 32 + 16 + h * 8);
  float4 e0d = *(const float4*)(edge + (size_t)e0 * 32 + 16 + h * 8 + 4);
  const float4 m0Alo = nbs4[vA0 * 4 + h],       m0Ahi = nbs4[vA0 * 4 + 2 + h];
  const float4 m0Blo = nbs4[(vA0 + 1) * 4 + h], m0Bhi = nbs4[(vA0 + 1) * 4 + 2 + h];

  __syncthreads();   // w1s ready

  // ================ pair 0 MFMA ================
  FragU ef0[2];
  ef0[0].u = pkcvt8(e0a, e0b);
  ef0[1].u = pkcvt8(e0c, e0d);

  f32x16 acc[4] = {};
#pragma unroll
  for (int kc = 0; kc < 8; kc++){
    FragU fa; fa.u = av0[kc];
#pragma unroll
    for (int nc2 = 0; nc2 < 4; nc2++){
      FragU bf_; bf_.u = w1s[(kc * 4 + nc2) * 64 + lane];
      acc[nc2] = __builtin_amdgcn_mfma_f32_32x32x16_bf16(fa.b, bf_.b, acc[nc2], 0, 0, 0);
    }
  }
#pragma unroll
  for (int kc = 8; kc < 10; kc++){
    FragU fa; fa.u = ef0[kc - 8].u;
#pragma unroll
    for (int nc2 = 0; nc2 < 4; nc2++){
      FragU bf_; bf_.u = w1s[(kc * 4 + nc2) * 64 + lane];
      acc[nc2] = __builtin_amdgcn_mfma_f32_32x32x16_bf16(fa.b, bf_.b, acc[nc2], 0, 0, 0);
    }
  }

  // ---- issue pair-1 gathers NOW (latency hidden behind pair-0 epilogue VALU) ----
  const int a1 = aadj[(vA0 + 2 + vsel) * 16 + nb];
  const int e1 = badj[(vA0 + 2 + vsel) * 16 + nb];
  ushort8v av1[8];
  {
    const ushort8v* arow = (const ushort8v*)(vfbf + (size_t)a1 * 128 + h * 8);
#pragma unroll
    for (int kc = 0; kc < 8; kc++) av1[kc] = arow[kc * 2];
  }
  float4 e1a = *(const float4*)(edge + (size_t)e1 * 32 + h * 8);
  float4 e1b = *(const float4*)(edge + (size_t)e1 * 32 + h * 8 + 4);
  float4 e1c = *(const float4*)(edge + (size_t)e1 * 32 + 16 + h * 8);
  float4 e1d = *(const float4*)(edge + (size_t)e1 * 32 + 16 + h * 8 + 4);
  const float4 m1Alo = nbs4[(vA0 + 2) * 4 + h], m1Ahi = nbs4[(vA0 + 2) * 4 + 2 + h];
  const float4 m1Blo = nbs4[(vA0 + 3) * 4 + h], m1Bhi = nbs4[(vA0 + 3) * 4 + 2 + h];

  // ---- pair-0 epilogue: +b1, GELU, mask-weight, reduce; C row=(reg&3)+8*(reg>>2)+4*h ----
  {
    const int row = wid * 4;
#pragma unroll
    for (int nc2 = 0; nc2 < 4; nc2++){
      const float bb = b1v[nc2];
      f32x16 ac = acc[nc2];
      float sA = gelu_f(ac[0] + bb) * m0Alo.x + gelu_f(ac[1] + bb) * m0Alo.y
               + gelu_f(ac[2] + bb) * m0Alo.z + gelu_f(ac[3] + bb) * m0Alo.w
               + gelu_f(ac[4] + bb) * m0Ahi.x + gelu_f(ac[5] + bb) * m0Ahi.y
               + gelu_f(ac[6] + bb) * m0Ahi.z + gelu_f(ac[7] + bb) * m0Ahi.w;
      float sB = gelu_f(ac[8] + bb) * m0Blo.x + gelu_f(ac[9] + bb) * m0Blo.y
               + gelu_f(ac[10] + bb) * m0Blo.z + gelu_f(ac[11] + bb) * m0Blo.w
               + gelu_f(ac[12] + bb) * m0Bhi.x + gelu_f(ac[13] + bb) * m0Bhi.y
               + gelu_f(ac[14] + bb) * m0Bhi.z + gelu_f(ac[15] + bb) * m0Bhi.w;
      sA += __shfl_xor(sA, 32, 64);
      sB += __shfl_xor(sB, 32, 64);
      if (h == 0) nl_lds[row * NLSTR + nc2 * 32 + n32] = f2bf(sA);
      else        nl_lds[(row + 1) * NLSTR + nc2 * 32 + n32] = f2bf(sB);
    }
  }

  // ================ pair 1 MFMA + epilogue ================
  {
    FragU ef1[2];
    ef1[0].u = pkcvt8(e1a, e1b);
    ef1[1].u = pkcvt8(e1c, e1d);
    f32x16 acc1[4] = {};
#pragma unroll
    for (int kc = 0; kc < 8; kc++){
      FragU fa; fa.u = av1[kc];
#pragma unroll
      for (int nc2 = 0; nc2 < 4; nc2++){
        FragU bf_; bf_.u = w1s[(kc * 4 + nc2) * 64 + lane];
        acc1[nc2] = __builtin_amdgcn_mfma_f32_32x32x16_bf16(fa.b, bf_.b, acc1[nc2], 0, 0, 0);
      }
    }
#pragma unroll
    for (int kc = 8; kc < 10; kc++){
      FragU fa; fa.u = ef1[kc - 8].u;
#pragma unroll
      for (int nc2 = 0; nc2 < 4; nc2++){
        FragU bf_; bf_.u = w1s[(kc * 4 + nc2) * 64 + lane];
        acc1[nc2] = __builtin_amdgcn_mfma_f32_32x32x16_bf16(fa.b, bf_.b, acc1[nc2], 0, 0, 0);
      }
    }
    const int row = wid * 4 + 2;
#pragma unroll
    for (int nc2 = 0; nc2 < 4; nc2++){
      const float bb = b1v[nc2];
      f32x16 ac = acc1[nc2];
      float sA = gelu_f(ac[0] + bb) * m1Alo.x + gelu_f(ac[1] + bb) * m1Alo.y
               + gelu_f(ac[2] + bb) * m1Alo.z + gelu_f(ac[3] + bb) * m1Alo.w
               + gelu_f(ac[4] + bb) * m1Ahi.x + gelu_f(ac[5] + bb) * m1Ahi.y
               + gelu_f(ac[6] + bb) * m1Ahi.z + gelu_f(ac[7] + bb) * m1Ahi.w;
      float sB = gelu_f(ac[8] + bb) * m1Blo.x + gelu_f(ac[9] + bb) * m1Blo.y
               + gelu_f(ac[10] + bb) * m1Blo.z + gelu_f(ac[11] + bb) * m1Blo.w
               + gelu_f(ac[12] + bb) * m1Bhi.x + gelu_f(ac[13] + bb) * m1Bhi.y
               + gelu_f(ac[14] + bb) * m1Bhi.z + gelu_f(ac[15] + bb) * m1Bhi.w;
      sA += __shfl_xor(sA, 32, 64);
      sB += __shfl_xor(sB, 32, 64);
      if (h == 0) nl_lds[row * NLSTR + nc2 * 32 + n32] = f2bf(sA);
      else        nl_lds[(row + 1) * NLSTR + nc2 * 32 + n32] = f2bf(sB);
    }
  }
  __syncthreads();

  // ---------------- stage 2: wave wid computes output cols [wid*32, wid*32+32) --------
  const int nc0 = 2 * wid;
  const float th = logf(lamda[0] / (float)lval[0] + 1.0f);
  const float al = alpha[0];

  f32x4 acc2[2] = {};
#pragma unroll
  for (int kc = 0; kc < 8; kc++){
    FragU a;
    if (kc < 4) a.u = *(const ushort8v*)(nl_lds + col * NLSTR + kc * 32 + quad * 8);
    else        a.u = *(const ushort8v*)(vfbf + (size_t)(v0 + col) * 128 + (kc - 4) * 32 + quad * 8);
#pragma unroll
    for (int p = 0; p < 2; p++){
      FragU bf_;
      bf_.u = *(const ushort8v*)(w2f + ((kc * 8 + nc0 + p) * 64 + lane) * 8);
      acc2[p] = __builtin_amdgcn_mfma_f32_16x16x32_bf16(a.b, bf_.b, acc2[p], 0, 0, 0);
    }
  }

  float sup[2][4];
#pragma unroll
  for (int p = 0; p < 2; p++){
    const int d = (nc0 + p) * 16 + col;
    const float bb = b2[d];
#pragma unroll
    for (int r = 0; r < 4; r++){
      const int vtx = v0 + quad * 4 + r;
      float hi = acc2[p][r] + bb;
      float s = (1.f - al) * hi + al * h0[vtx * 128 + d];
      sup[p][r] = s;
      sup_lds[(quad * 4 + r) * NLSTR + d] = f2bf(s);
    }
  }
  __syncthreads();

  f32x4 acc3[2] = {};
#pragma unroll
  for (int kc = 0; kc < 4; kc++){
    FragU a;
    a.u = *(const ushort8v*)(sup_lds + col * NLSTR + kc * 32 + quad * 8);
#pragma unroll
    for (int p = 0; p < 2; p++){
      FragU bf_;
      bf_.u = *(const ushort8v*)(w3f + ((kc * 8 + nc0 + p) * 64 + lane) * 8);
      acc3[p] = __builtin_amdgcn_mfma_f32_16x16x32_bf16(a.b, bf_.b, acc3[p], 0, 0, 0);
    }
  }

#pragma unroll
  for (int p = 0; p < 2; p++){
    const int d = (nc0 + p) * 16 + col;
    const float bb = b3[d];
#pragma unroll
    for (int r = 0; r < 4; r++){
      const int vtx = v0 + quad * 4 + r;
      float res = bf2f(vfbf[(size_t)vtx * 128 + d]);
      out[vtx * 128 + d] = th * (acc3[p][r] + bb) + (1.f - th) * sup[p][r] + res;
    }
  }
}

extern "C" void kernel_launch(void* const* d_in, const int* in_sizes, int n_in,
                              void* d_out, int out_size, void* d_ws, size_t ws_size,
                              hipStream_t stream)
{
  const float* vfp  = (const float*)d_in[0];
  const int*   aadj = (const int*)d_in[1];
  const int*   badj = (const int*)d_in[2];
  const float* h0   = (const float*)d_in[3];
  const float* lam  = (const float*)d_in[4];
  const float* alp  = (const float*)d_in[5];
  const int*   lv   = (const int*)d_in[6];
  const float* edge = (const float*)d_in[7];
  // d_in[8] vertex_mask: unused by the reference math
  const float* nbs  = (const float*)d_in[9];
  const float* W1   = (const float*)d_in[10];
  const float* b1   = (const float*)d_in[11];
  const float* W2   = (const float*)d_in[12];
  const float* b2   = (const float*)d_in[13];
  const float* W3   = (const float*)d_in[14];
  const float* b3   = (const float*)d_in[15];
  float* out = (float*)d_out;

  // ws layout (ushorts): w1f [0,20480) | w2f [20480,53248) | w3f [53248,69632)
  //                      | vfbf [69632, 69632+2097152)
  unsigned short* w1f  = (unsigned short*)d_ws;
  unsigned short* w2f  = w1f + 20480;
  unsigned short* w3f  = w2f + 32768;
  unsigned short* vfbf = w3f + 16384;

  prep_kernel<<<1058, 256, 0, stream>>>(vfp, W1, W2, W3, vfbf, w1f, w2f, w3f);
  fused_kernel<<<1024, 256, 0, stream>>>(vfbf, aadj, badj, edge, nbs, h0,
                                         w1f, w2f, w3f, b1, b2, b3, lam, alp, lv, out);
}

// Round 6
// 147.285 us; speedup vs baseline: 1.0646x; 1.0646x over previous
//
#include <hip/hip_runtime.h>
#include <hip/hip_bf16.h>
#include <math.h>

// Problem constants: B=32 V=512 K=16 D=128 E=32 NE=8192 -> BV=16384 vertices
#define NLSTR 136   // LDS row stride (ushorts) for 16x128 tiles
#define ASTR  168   // LDS row stride (ushorts) for A tiles: 160+8 pad, 336B (16B-aligned)

typedef __bf16 bf16x8 __attribute__((ext_vector_type(8)));
typedef float f32x4 __attribute__((ext_vector_type(4)));
typedef float f32x16 __attribute__((ext_vector_type(16)));
typedef unsigned short ushort8v __attribute__((ext_vector_type(8)));

union FragU { ushort8v u; bf16x8 b; };

static __device__ inline unsigned short f2bf(float f){
  unsigned u = __float_as_uint(f);
  u += 0x7fffu + ((u >> 16) & 1u);   // RNE
  return (unsigned short)(u >> 16);
}
static __device__ inline float bf2f(unsigned short u){
  return __uint_as_float(((unsigned)u) << 16);
}
static __device__ inline unsigned pk2(float a, float b){
  union { __hip_bfloat162 h; unsigned u; } r;
  r.h = __float22bfloat162_rn(float2{a, b});
  return r.u;
}
static __device__ inline ushort8v pkcvt8(float4 a, float4 b){
  union { unsigned u[4]; ushort8v v; } r;
  r.u[0] = pk2(a.x, a.y); r.u[1] = pk2(a.z, a.w);
  r.u[2] = pk2(b.x, b.y); r.u[3] = pk2(b.z, b.w);
  return r.v;
}

// tanh-form GELU (max err ~3e-4 vs exact erf-GELU)
static __device__ inline float gelu_f(float x){
  float u = x * x;
  float p = fmaf(u, 0.07135481283f, 1.5957691216f);
  float t = x * p;
  float e = __builtin_amdgcn_exp2f(t * -1.44269504f);
  return x * __builtin_amdgcn_rcpf(1.0f + e);
}

// ---------------- prep: bf16 vertex table + fragment-order bf16 weights ----------------
// w1f: 32x32x16 B-frags, STRIP-MAJOR: frag (nc2*10+kc), elem j of lane:
//      W1[(nc2*32+(lane&31))*160 + kc*16 + (lane>>5)*8 + j]   (wave strip = contiguous 10KB)
// w2f/w3f: 16x16x32 B-frags as before.
__global__ __launch_bounds__(256) void prep_kernel(
    const float* __restrict__ vf, const float* __restrict__ W1,
    const float* __restrict__ W2, const float* __restrict__ W3,
    unsigned short* __restrict__ vfbf, unsigned short* __restrict__ w1f,
    unsigned short* __restrict__ w2f, unsigned short* __restrict__ w3f)
{
  int t = blockIdx.x * 256 + threadIdx.x;
  if (t < 262144){                       // 16384*128 / 8
    const float4* src = (const float4*)vf;
    float4 x = src[t * 2], y = src[t * 2 + 1];
    *(ushort8v*)(vfbf + t * 8) = pkcvt8(x, y);
    return;
  }
  int t2 = t - 262144;
  const float* s;
  unsigned short* d;
  if (t2 < 2560){                        // w1f: 4nc2 x 10kc strip-major
    int fragid = t2 >> 6, lane = t2 & 63;
    int nc2 = fragid / 10, kc = fragid % 10, n = lane & 31, h = lane >> 5;
    s = W1 + (nc2 * 32 + n) * 160 + kc * 16 + h * 8;
    d = w1f + t2 * 8;
  } else if (t2 < 6656){                 // w2f: 8kc x 8nc
    int t3 = t2 - 2560;
    int fragid = t3 >> 6, lane = t3 & 63;
    int kc = fragid >> 3, nc = fragid & 7, col = lane & 15, quad = lane >> 4;
    s = W2 + (nc * 16 + col) * 256 + kc * 32 + quad * 8;
    d = w2f + t3 * 8;
  } else if (t2 < 8704){                 // w3f: 4kc x 8nc
    int t3 = t2 - 6656;
    int fragid = t3 >> 6, lane = t3 & 63;
    int kc = fragid >> 3, nc = fragid & 7, col = lane & 15, quad = lane >> 4;
    s = W3 + (nc * 16 + col) * 128 + kc * 32 + quad * 8;
    d = w3f + t3 * 8;
  } else return;
#pragma unroll
  for (int j = 0; j < 8; j++) d[j] = f2bf(s[j]);
}

// ---------------- fused ----------------
// grid 1024 x 256thr. Block = 16 vertices = 8 pairs. B-IN-REGISTERS structure:
// wave wid holds W1 B-frags for cols [wid*32,wid*32+32) in 40 VGPRs for the whole
// kernel (zero B traffic in the K-loop). A (32 gathered neighbor rows / pair) is
// cooperatively staged into double-buffered LDS; 1 barrier per pair; gathers for
// pair p+1 issued before pair-p compute.
__global__ __launch_bounds__(256) void fused_kernel(
    const unsigned short* __restrict__ vfbf,
    const int* __restrict__ aadj, const int* __restrict__ badj,
    const float* __restrict__ edge, const float* __restrict__ nbs,
    const float* __restrict__ h0,
    const unsigned short* __restrict__ w1f, const unsigned short* __restrict__ w2f,
    const unsigned short* __restrict__ w3f,
    const float* __restrict__ b1, const float* __restrict__ b2, const float* __restrict__ b3,
    const float* __restrict__ lamda, const float* __restrict__ alpha,
    const int* __restrict__ lval,
    float* __restrict__ out)
{
  __shared__ __align__(16) unsigned short abuf[2][32 * ASTR];   // 2 x 10.5 KB
  __shared__ __align__(16) unsigned short nl_lds[16 * NLSTR];
  __shared__ __align__(16) unsigned short sup_lds[16 * NLSTR];
  const int wid  = threadIdx.x >> 6;
  const int lane = threadIdx.x & 63;
  const int n32  = lane & 31;
  const int h    = lane >> 5;
  const int col  = lane & 15;
  const int quad = lane >> 4;
  const int v0   = blockIdx.x * 16;

  // ---- B strip into registers (wave wid -> nc2 = wid), held all of stage 1 ----
  FragU bw[10];
#pragma unroll
  for (int kc = 0; kc < 10; kc++)
    bw[kc].u = *(const ushort8v*)(w1f + ((wid * 10 + kc) * 64 + lane) * 8);

  const float bb1 = b1[wid * 32 + n32];
  const float4* nbs4 = (const float4*)nbs;

  // staging thread mapping: 8 threads per A row
  const int srow = threadIdx.x >> 3;   // 0..31: row (vertex-half + neighbor)
  const int ssub = threadIdx.x & 7;    // 0..7

  // ---- issue + commit pair-0 staging ----
  ushort8v sv0, sv1; float4 se;
  {
    const int vtx = v0 + (srow >> 4), nb = srow & 15;
    const int a = aadj[vtx * 16 + nb], e = badj[vtx * 16 + nb];
    const ushort8v* vs = (const ushort8v*)(vfbf + (size_t)a * 128 + ssub * 16);
    sv0 = vs[0]; sv1 = vs[1];
    se = *(const float4*)(edge + (size_t)e * 32 + ssub * 4);
  }
  {
    unsigned short* dst = abuf[0] + srow * ASTR + ssub * 16;
    *(ushort8v*)dst = sv0; *(ushort8v*)(dst + 8) = sv1;
    unsigned* ed = (unsigned*)(abuf[0] + srow * ASTR + 128 + ssub * 4);
    ed[0] = pk2(se.x, se.y); ed[1] = pk2(se.z, se.w);
  }

#pragma unroll 1
  for (int p = 0; p < 8; ++p){
    __syncthreads();                         // abuf[p&1] ready; prior reads of abuf[(p+1)&1] done
    // ---- issue gathers for pair p+1 (latency hidden behind pair-p compute) ----
    if (p < 7){
      const int vtx = v0 + 2 * (p + 1) + (srow >> 4), nb = srow & 15;
      const int a = aadj[vtx * 16 + nb], e = badj[vtx * 16 + nb];
      const ushort8v* vs = (const ushort8v*)(vfbf + (size_t)a * 128 + ssub * 16);
      sv0 = vs[0]; sv1 = vs[1];
      se = *(const float4*)(edge + (size_t)e * 32 + ssub * 4);
    }

    // ---- pair-p MFMA: A from LDS, B from registers ----
    const unsigned short* ab = abuf[p & 1] + n32 * ASTR + h * 8;
    f32x16 acc = {};
#pragma unroll
    for (int kc = 0; kc < 10; kc++){
      FragU fa;
      fa.u = *(const ushort8v*)(ab + kc * 16);
      acc = __builtin_amdgcn_mfma_f32_32x32x16_bf16(fa.b, bw[kc].b, acc, 0, 0, 0);
    }

    // ---- epilogue: +b1, GELU, mask, reduce; C row=(reg&3)+8*(reg>>2)+4*h ----
    {
      const int vA = v0 + 2 * p;
      const float4 mAlo = nbs4[vA * 4 + h],       mAhi = nbs4[vA * 4 + 2 + h];
      const float4 mBlo = nbs4[(vA + 1) * 4 + h], mBhi = nbs4[(vA + 1) * 4 + 2 + h];
      float sA = gelu_f(acc[0] + bb1) * mAlo.x + gelu_f(acc[1] + bb1) * mAlo.y
               + gelu_f(acc[2] + bb1) * mAlo.z + gelu_f(acc[3] + bb1) * mAlo.w
               + gelu_f(acc[4] + bb1) * mAhi.x + gelu_f(acc[5] + bb1) * mAhi.y
               + gelu_f(acc[6] + bb1) * mAhi.z + gelu_f(acc[7] + bb1) * mAhi.w;
      float sB = gelu_f(acc[8] + bb1) * mBlo.x + gelu_f(acc[9] + bb1) * mBlo.y
               + gelu_f(acc[10] + bb1) * mBlo.z + gelu_f(acc[11] + bb1) * mBlo.w
               + gelu_f(acc[12] + bb1) * mBhi.x + gelu_f(acc[13] + bb1) * mBhi.y
               + gelu_f(acc[14] + bb1) * mBhi.z + gelu_f(acc[15] + bb1) * mBhi.w;
      sA += __shfl_xor(sA, 32, 64);
      sB += __shfl_xor(sB, 32, 64);
      if (h == 0) nl_lds[(2 * p)     * NLSTR + wid * 32 + n32] = f2bf(sA);
      else        nl_lds[(2 * p + 1) * NLSTR + wid * 32 + n32] = f2bf(sB);
    }

    // ---- commit pair-p+1 staging into abuf[(p+1)&1] ----
    if (p < 7){
      unsigned short* dst = abuf[(p + 1) & 1] + srow * ASTR + ssub * 16;
      *(ushort8v*)dst = sv0; *(ushort8v*)(dst + 8) = sv1;
      unsigned* ed = (unsigned*)(abuf[(p + 1) & 1] + srow * ASTR + 128 + ssub * 4);
      ed[0] = pk2(se.x, se.y); ed[1] = pk2(se.z, se.w);
    }
  }
  __syncthreads();

  // ---------------- stage 2: wave wid computes output cols [wid*32, wid*32+32) --------
  const int nc0 = 2 * wid;
  const float th = logf(lamda[0] / (float)lval[0] + 1.0f);
  const float al = alpha[0];

  f32x4 acc2[2] = {};
#pragma unroll
  for (int kc = 0; kc < 8; kc++){
    FragU a;
    if (kc < 4) a.u = *(const ushort8v*)(nl_lds + col * NLSTR + kc * 32 + quad * 8);
    else        a.u = *(const ushort8v*)(vfbf + (size_t)(v0 + col) * 128 + (kc - 4) * 32 + quad * 8);
#pragma unroll
    for (int pq = 0; pq < 2; pq++){
      FragU bf_;
      bf_.u = *(const ushort8v*)(w2f + ((kc * 8 + nc0 + pq) * 64 + lane) * 8);
      acc2[pq] = __builtin_amdgcn_mfma_f32_16x16x32_bf16(a.b, bf_.b, acc2[pq], 0, 0, 0);
    }
  }

  float sup[2][4];
#pragma unroll
  for (int pq = 0; pq < 2; pq++){
    const int d = (nc0 + pq) * 16 + col;
    const float bb = b2[d];
#pragma unroll
    for (int r = 0; r < 4; r++){
      const int vtx = v0 + quad * 4 + r;
      float hi = acc2[pq][r] + bb;
      float s = (1.f - al) * hi + al * h0[vtx * 128 + d];
      sup[pq][r] = s;
      sup_lds[(quad * 4 + r) * NLSTR + d] = f2bf(s);
    }
  }
  __syncthreads();

  f32x4 acc3[2] = {};
#pragma unroll
  for (int kc = 0; kc < 4; kc++){
    FragU a;
    a.u = *(const ushort8v*)(sup_lds + col * NLSTR + kc * 32 + quad * 8);
#pragma unroll
    for (int pq = 0; pq < 2; pq++){
      FragU bf_;
      bf_.u = *(const ushort8v*)(w3f + ((kc * 8 + nc0 + pq) * 64 + lane) * 8);
      acc3[pq] = __builtin_amdgcn_mfma_f32_16x16x32_bf16(a.b, bf_.b, acc3[pq], 0, 0, 0);
    }
  }

#pragma unroll
  for (int pq = 0; pq < 2; pq++){
    const int d = (nc0 + pq) * 16 + col;
    const float bb = b3[d];
#pragma unroll
    for (int r = 0; r < 4; r++){
      const int vtx = v0 + quad * 4 + r;
      float res = bf2f(vfbf[(size_t)vtx * 128 + d]);
      out[vtx * 128 + d] = th * (acc3[pq][r] + bb) + (1.f - th) * sup[pq][r] + res;
    }
  }
}

extern "C" void kernel_launch(void* const* d_in, const int* in_sizes, int n_in,
                              void* d_out, int out_size, void* d_ws, size_t ws_size,
                              hipStream_t stream)
{
  const float* vfp  = (const float*)d_in[0];
  const int*   aadj = (const int*)d_in[1];
  const int*   badj = (const int*)d_in[2];
  const float* h0   = (const float*)d_in[3];
  const float* lam  = (const float*)d_in[4];
  const float* alp  = (const float*)d_in[5];
  const int*   lv   = (const int*)d_in[6];
  const float* edge = (const float*)d_in[7];
  // d_in[8] vertex_mask: unused by the reference math
  const float* nbs  = (const float*)d_in[9];
  const float* W1   = (const float*)d_in[10];
  const float* b1   = (const float*)d_in[11];
  const float* W2   = (const float*)d_in[12];
  const float* b2   = (const float*)d_in[13];
  const float* W3   = (const float*)d_in[14];
  const float* b3   = (const float*)d_in[15];
  float* out = (float*)d_out;

  // ws layout (ushorts): w1f [0,20480) | w2f [20480,53248) | w3f [53248,69632)
  //                      | vfbf [69632, 69632+2097152)
  unsigned short* w1f  = (unsigned short*)d_ws;
  unsigned short* w2f  = w1f + 20480;
  unsigned short* w3f  = w2f + 32768;
  unsigned short* vfbf = w3f + 16384;

  prep_kernel<<<1058, 256, 0, stream>>>(vfp, W1, W2, W3, vfbf, w1f, w2f, w3f);
  fused_kernel<<<1024, 256, 0, stream>>>(vfbf, aadj, badj, edge, nbs, h0,
                                         w1f, w2f, w3f, b1, b2, b3, lam, alp, lv, out);
}

// Round 7
// 143.386 us; speedup vs baseline: 1.0936x; 1.0272x over previous
//
#include <hip/hip_runtime.h>
#include <hip/hip_bf16.h>
#include <math.h>

// Problem constants: B=32 V=512 K=16 D=128 E=32 NE=8192 -> BV=16384 vertices
#define NLSTR 136   // LDS row stride (ushorts) for 16x128 tiles
#define ASTR  168   // LDS row stride (ushorts) for A tiles: 160+8 pad, 336B (16B-aligned)

typedef __bf16 bf16x8 __attribute__((ext_vector_type(8)));
typedef float f32x4 __attribute__((ext_vector_type(4)));
typedef float f32x16 __attribute__((ext_vector_type(16)));
typedef unsigned short ushort8v __attribute__((ext_vector_type(8)));

union FragU { ushort8v u; bf16x8 b; };

static __device__ inline unsigned short f2bf(float f){
  unsigned u = __float_as_uint(f);
  u += 0x7fffu + ((u >> 16) & 1u);   // RNE
  return (unsigned short)(u >> 16);
}
static __device__ inline float bf2f(unsigned short u){
  return __uint_as_float(((unsigned)u) << 16);
}
static __device__ inline unsigned pk2(float a, float b){
  union { __hip_bfloat162 h; unsigned u; } r;
  r.h = __float22bfloat162_rn(float2{a, b});
  return r.u;
}
static __device__ inline ushort8v pkcvt8(float4 a, float4 b){
  union { unsigned u[4]; ushort8v v; } r;
  r.u[0] = pk2(a.x, a.y); r.u[1] = pk2(a.z, a.w);
  r.u[2] = pk2(b.x, b.y); r.u[3] = pk2(b.z, b.w);
  return r.v;
}

// tanh-form GELU (max err ~3e-4 vs exact erf-GELU)
static __device__ inline float gelu_f(float x){
  float u = x * x;
  float p = fmaf(u, 0.07135481283f, 1.5957691216f);
  float t = x * p;
  float e = __builtin_amdgcn_exp2f(t * -1.44269504f);
  return x * __builtin_amdgcn_rcpf(1.0f + e);
}

// ---------------- prep: bf16 vertex table + fragment-order bf16 weights ----------------
// w1f: 32x32x16 B-frags, STRIP-MAJOR: frag (nc2*10+kc), elem j of lane:
//      W1[(nc2*32+(lane&31))*160 + kc*16 + (lane>>5)*8 + j]   (wave strip = contiguous 10KB)
// w2f/w3f: 16x16x32 B-frags as before.
__global__ __launch_bounds__(256) void prep_kernel(
    const float* __restrict__ vf, const float* __restrict__ W1,
    const float* __restrict__ W2, const float* __restrict__ W3,
    unsigned short* __restrict__ vfbf, unsigned short* __restrict__ w1f,
    unsigned short* __restrict__ w2f, unsigned short* __restrict__ w3f)
{
  int t = blockIdx.x * 256 + threadIdx.x;
  if (t < 262144){                       // 16384*128 / 8
    const float4* src = (const float4*)vf;
    float4 x = src[t * 2], y = src[t * 2 + 1];
    *(ushort8v*)(vfbf + t * 8) = pkcvt8(x, y);
    return;
  }
  int t2 = t - 262144;
  const float* s;
  unsigned short* d;
  if (t2 < 2560){                        // w1f: 4nc2 x 10kc strip-major
    int fragid = t2 >> 6, lane = t2 & 63;
    int nc2 = fragid / 10, kc = fragid % 10, n = lane & 31, h = lane >> 5;
    s = W1 + (nc2 * 32 + n) * 160 + kc * 16 + h * 8;
    d = w1f + t2 * 8;
  } else if (t2 < 6656){                 // w2f: 8kc x 8nc
    int t3 = t2 - 2560;
    int fragid = t3 >> 6, lane = t3 & 63;
    int kc = fragid >> 3, nc = fragid & 7, col = lane & 15, quad = lane >> 4;
    s = W2 + (nc * 16 + col) * 256 + kc * 32 + quad * 8;
    d = w2f + t3 * 8;
  } else if (t2 < 8704){                 // w3f: 4kc x 8nc
    int t3 = t2 - 6656;
    int fragid = t3 >> 6, lane = t3 & 63;
    int kc = fragid >> 3, nc = fragid & 7, col = lane & 15, quad = lane >> 4;
    s = W3 + (nc * 16 + col) * 128 + kc * 32 + quad * 8;
    d = w3f + t3 * 8;
  } else return;
#pragma unroll
  for (int j = 0; j < 8; j++) d[j] = f2bf(s[j]);
}

// ---------------- fused ----------------
// grid 1024 x 256thr. Block = 16 vertices = 8 pairs. B-in-registers (wave wid owns
// cols [wid*32,+32), 10 B-frags resident). A double-buffered in LDS. Schedule per
// pair p: barrier -> commit p+1 (gathers issued at iter p-1: ~2 iterations old,
// covers 900cy HBM edge-miss) -> issue gathers p+2 -> compute p -> epilogue.
// All adjacency indices preloaded (removes idx->gather chain from steady state).
__global__ __launch_bounds__(256) void fused_kernel(
    const unsigned short* __restrict__ vfbf,
    const int* __restrict__ aadj, const int* __restrict__ badj,
    const float* __restrict__ edge, const float* __restrict__ nbs,
    const float* __restrict__ h0,
    const unsigned short* __restrict__ w1f, const unsigned short* __restrict__ w2f,
    const unsigned short* __restrict__ w3f,
    const float* __restrict__ b1, const float* __restrict__ b2, const float* __restrict__ b3,
    const float* __restrict__ lamda, const float* __restrict__ alpha,
    const int* __restrict__ lval,
    float* __restrict__ out)
{
  __shared__ __align__(16) unsigned short abuf[2][32 * ASTR];   // 2 x 10.5 KB
  __shared__ __align__(16) unsigned short nl_lds[16 * NLSTR];
  __shared__ __align__(16) unsigned short sup_lds[16 * NLSTR];
  const int wid  = threadIdx.x >> 6;
  const int lane = threadIdx.x & 63;
  const int n32  = lane & 31;
  const int h    = lane >> 5;
  const int col  = lane & 15;
  const int quad = lane >> 4;
  const int v0   = blockIdx.x * 16;

  // staging thread mapping: 8 threads per A row
  const int srow = threadIdx.x >> 3;   // 0..31: row (vertex-half + neighbor slot)
  const int ssub = threadIdx.x & 7;    // 0..7

  // ---- preload ALL pair indices (coalesced; kills idx->gather dependent chain) ----
  int a_all[8], e_all[8];
  {
    const int base = (v0 + (srow >> 4)) * 16 + (srow & 15);
#pragma unroll
    for (int p = 0; p < 8; p++){
      a_all[p] = aadj[base + 32 * p];
      e_all[p] = badj[base + 32 * p];
    }
  }

  // ---- B strip into registers (wave wid -> nc2 = wid), held all of stage 1 ----
  FragU bw[10];
#pragma unroll
  for (int kc = 0; kc < 10; kc++)
    bw[kc].u = *(const ushort8v*)(w1f + ((wid * 10 + kc) * 64 + lane) * 8);

  const float bb1 = b1[wid * 32 + n32];
  const float4* nbs4 = (const float4*)nbs;

  ushort8v sv0, sv1; float4 se;
  // issue pair-0 gathers
  {
    const ushort8v* vs = (const ushort8v*)(vfbf + (size_t)a_all[0] * 128 + ssub * 16);
    sv0 = vs[0]; sv1 = vs[1];
    se = *(const float4*)(edge + (size_t)e_all[0] * 32 + ssub * 4);
  }
  // commit pair-0 into abuf[0]
  {
    unsigned short* dst = abuf[0] + srow * ASTR + ssub * 16;
    *(ushort8v*)dst = sv0; *(ushort8v*)(dst + 8) = sv1;
    unsigned* ed = (unsigned*)(abuf[0] + srow * ASTR + 128 + ssub * 4);
    ed[0] = pk2(se.x, se.y); ed[1] = pk2(se.z, se.w);
  }
  // issue pair-1 gathers
  {
    const ushort8v* vs = (const ushort8v*)(vfbf + (size_t)a_all[1] * 128 + ssub * 16);
    sv0 = vs[0]; sv1 = vs[1];
    se = *(const float4*)(edge + (size_t)e_all[1] * 32 + ssub * 4);
  }

#pragma unroll 1
  for (int p = 0; p < 8; ++p){
    __syncthreads();   // all waves done reading abuf[(p+1)&1] (at iter p-1) + pair-p commits visible

    // ---- commit pair p+1 (gathers ~2 iterations old) ----
    if (p < 7){
      unsigned short* dst = abuf[(p + 1) & 1] + srow * ASTR + ssub * 16;
      *(ushort8v*)dst = sv0; *(ushort8v*)(dst + 8) = sv1;
      unsigned* ed = (unsigned*)(abuf[(p + 1) & 1] + srow * ASTR + 128 + ssub * 4);
      ed[0] = pk2(se.x, se.y); ed[1] = pk2(se.z, se.w);
    }
    // ---- issue gathers for pair p+2 ----
    if (p < 6){
      const ushort8v* vs = (const ushort8v*)(vfbf + (size_t)a_all[p + 2] * 128 + ssub * 16);
      sv0 = vs[0]; sv1 = vs[1];
      se = *(const float4*)(edge + (size_t)e_all[p + 2] * 32 + ssub * 4);
    }

    // ---- pair-p MFMA: A from LDS, B from registers ----
    const unsigned short* ab = abuf[p & 1] + n32 * ASTR + h * 8;
    f32x16 acc = {};
#pragma unroll
    for (int kc = 0; kc < 10; kc++){
      FragU fa;
      fa.u = *(const ushort8v*)(ab + kc * 16);
      acc = __builtin_amdgcn_mfma_f32_32x32x16_bf16(fa.b, bw[kc].b, acc, 0, 0, 0);
    }

    // ---- epilogue: +b1, GELU, mask, reduce; C row=(reg&3)+8*(reg>>2)+4*h ----
    {
      const int vA = v0 + 2 * p;
      const float4 mAlo = nbs4[vA * 4 + h],       mAhi = nbs4[vA * 4 + 2 + h];
      const float4 mBlo = nbs4[(vA + 1) * 4 + h], mBhi = nbs4[(vA + 1) * 4 + 2 + h];
      float sA = gelu_f(acc[0] + bb1) * mAlo.x + gelu_f(acc[1] + bb1) * mAlo.y
               + gelu_f(acc[2] + bb1) * mAlo.z + gelu_f(acc[3] + bb1) * mAlo.w
               + gelu_f(acc[4] + bb1) * mAhi.x + gelu_f(acc[5] + bb1) * mAhi.y
               + gelu_f(acc[6] + bb1) * mAhi.z + gelu_f(acc[7] + bb1) * mAhi.w;
      float sB = gelu_f(acc[8] + bb1) * mBlo.x + gelu_f(acc[9] + bb1) * mBlo.y
               + gelu_f(acc[10] + bb1) * mBlo.z + gelu_f(acc[11] + bb1) * mBlo.w
               + gelu_f(acc[12] + bb1) * mBhi.x + gelu_f(acc[13] + bb1) * mBhi.y
               + gelu_f(acc[14] + bb1) * mBhi.z + gelu_f(acc[15] + bb1) * mBhi.w;
      sA += __shfl_xor(sA, 32, 64);
      sB += __shfl_xor(sB, 32, 64);
      if (h == 0) nl_lds[(2 * p)     * NLSTR + wid * 32 + n32] = f2bf(sA);
      else        nl_lds[(2 * p + 1) * NLSTR + wid * 32 + n32] = f2bf(sB);
    }
  }
  __syncthreads();

  // ---------------- stage 2: wave wid computes output cols [wid*32, wid*32+32) --------
  const int nc0 = 2 * wid;
  const float th = logf(lamda[0] / (float)lval[0] + 1.0f);
  const float al = alpha[0];

  f32x4 acc2[2] = {};
#pragma unroll
  for (int kc = 0; kc < 8; kc++){
    FragU a;
    if (kc < 4) a.u = *(const ushort8v*)(nl_lds + col * NLSTR + kc * 32 + quad * 8);
    else        a.u = *(const ushort8v*)(vfbf + (size_t)(v0 + col) * 128 + (kc - 4) * 32 + quad * 8);
#pragma unroll
    for (int pq = 0; pq < 2; pq++){
      FragU bf_;
      bf_.u = *(const ushort8v*)(w2f + ((kc * 8 + nc0 + pq) * 64 + lane) * 8);
      acc2[pq] = __builtin_amdgcn_mfma_f32_16x16x32_bf16(a.b, bf_.b, acc2[pq], 0, 0, 0);
    }
  }

  float sup[2][4];
#pragma unroll
  for (int pq = 0; pq < 2; pq++){
    const int d = (nc0 + pq) * 16 + col;
    const float bb = b2[d];
#pragma unroll
    for (int r = 0; r < 4; r++){
      const int vtx = v0 + quad * 4 + r;
      float hi = acc2[pq][r] + bb;
      float s = (1.f - al) * hi + al * h0[vtx * 128 + d];
      sup[pq][r] = s;
      sup_lds[(quad * 4 + r) * NLSTR + d] = f2bf(s);
    }
  }
  __syncthreads();

  f32x4 acc3[2] = {};
#pragma unroll
  for (int kc = 0; kc < 4; kc++){
    FragU a;
    a.u = *(const ushort8v*)(sup_lds + col * NLSTR + kc * 32 + quad * 8);
#pragma unroll
    for (int pq = 0; pq < 2; pq++){
      FragU bf_;
      bf_.u = *(const ushort8v*)(w3f + ((kc * 8 + nc0 + pq) * 64 + lane) * 8);
      acc3[pq] = __builtin_amdgcn_mfma_f32_16x16x32_bf16(a.b, bf_.b, acc3[pq], 0, 0, 0);
    }
  }

#pragma unroll
  for (int pq = 0; pq < 2; pq++){
    const int d = (nc0 + pq) * 16 + col;
    const float bb = b3[d];
#pragma unroll
    for (int r = 0; r < 4; r++){
      const int vtx = v0 + quad * 4 + r;
      float res = bf2f(vfbf[(size_t)vtx * 128 + d]);
      out[vtx * 128 + d] = th * (acc3[pq][r] + bb) + (1.f - th) * sup[pq][r] + res;
    }
  }
}

extern "C" void kernel_launch(void* const* d_in, const int* in_sizes, int n_in,
                              void* d_out, int out_size, void* d_ws, size_t ws_size,
                              hipStream_t stream)
{
  const float* vfp  = (const float*)d_in[0];
  const int*   aadj = (const int*)d_in[1];
  const int*   badj = (const int*)d_in[2];
  const float* h0   = (const float*)d_in[3];
  const float* lam  = (const float*)d_in[4];
  const float* alp  = (const float*)d_in[5];
  const int*   lv   = (const int*)d_in[6];
  const float* edge = (const float*)d_in[7];
  // d_in[8] vertex_mask: unused by the reference math
  const float* nbs  = (const float*)d_in[9];
  const float* W1   = (const float*)d_in[10];
  const float* b1   = (const float*)d_in[11];
  const float* W2   = (const float*)d_in[12];
  const float* b2   = (const float*)d_in[13];
  const float* W3   = (const float*)d_in[14];
  const float* b3   = (const float*)d_in[15];
  float* out = (float*)d_out;

  // ws layout (ushorts): w1f [0,20480) | w2f [20480,53248) | w3f [53248,69632)
  //                      | vfbf [69632, 69632+2097152)
  unsigned short* w1f  = (unsigned short*)d_ws;
  unsigned short* w2f  = w1f + 20480;
  unsigned short* w3f  = w2f + 32768;
  unsigned short* vfbf = w3f + 16384;

  prep_kernel<<<1058, 256, 0, stream>>>(vfp, W1, W2, W3, vfbf, w1f, w2f, w3f);
  fused_kernel<<<1024, 256, 0, stream>>>(vfbf, aadj, badj, edge, nbs, h0,
                                         w1f, w2f, w3f, b1, b2, b3, lam, alp, lv, out);
}